// Round 12
// baseline (192.288 us; speedup 1.0000x reference)
//
#include <hip/hip_runtime.h>
#include <hip/hip_bf16.h>
#include <math.h>

// Problem constants (fixed by setup_inputs)
#define B_  2
#define S_  2048
#define D_  1024
#define H_  16
#define HD_ 64
#define NE_ 3072   // 3*D
#define M_  4096   // B*S

typedef unsigned short ushort_t;
typedef __attribute__((ext_vector_type(8))) short bf16x8;
typedef __attribute__((ext_vector_type(8))) _Float16 f16x8;
typedef __attribute__((ext_vector_type(4))) float f32x4;
typedef __attribute__((ext_vector_type(4))) short s16x4;

// log2(e) folded into q-scale; softmax base folded into exp2 offset
#define QSCALE 0.18033688011112042f      // 0.125 * log2(e)
#define EXPOFF 46.166240909416444f       // 32 * log2(e)

__device__ __forceinline__ short f2bf(float f) {
    union { float f; unsigned u; } v; v.f = f;
    unsigned u = v.u;
    u += 0x7fffu + ((u >> 16) & 1u);   // round-to-nearest-even
    return (short)(u >> 16);
}
__device__ __forceinline__ ushort_t f2h(float f) {
    union { _Float16 h; ushort_t u; } v;
    v.h = (_Float16)f;                 // v_cvt_f16_f32, RTE
    return v.u;
}

// async global->LDS, 16B per lane; LDS dest = wave-uniform base + lane*16
__device__ __forceinline__ void async16(const ushort_t* g, ushort_t* l) {
    __builtin_amdgcn_global_load_lds(
        (const __attribute__((address_space(1))) void*)g,
        (__attribute__((address_space(3))) void*)l,
        16, 0, 0);
}

// ---------------------------------------------------------------------------
// fp32 -> fp16 conversion (8 elems/thread) — X, Wqkv, Wo
// ---------------------------------------------------------------------------
__global__ __launch_bounds__(256) void cvt_f16(const float* __restrict__ s,
                                               ushort_t* __restrict__ d, int n8) {
    int i = blockIdx.x * 256 + threadIdx.x;
    if (i >= n8) return;
    const float4* sp = (const float4*)s;
    float4 a = sp[2 * (size_t)i], b = sp[2 * (size_t)i + 1];
    f16x8 o;
    o[0] = (_Float16)a.x; o[1] = (_Float16)a.y; o[2] = (_Float16)a.z; o[3] = (_Float16)a.w;
    o[4] = (_Float16)b.x; o[5] = (_Float16)b.y; o[6] = (_Float16)b.z; o[7] = (_Float16)b.w;
    *(f16x8*)(d + 8 * (size_t)i) = o;
}

// ---------------------------------------------------------------------------
// RoPE cos/sin table: tab[s*32 + tt] = (cos(s*theta^(-tt/32)), sin(...)).
// 512 KB, one-shot, L2-resident during gemm_qkv.
// ---------------------------------------------------------------------------
__global__ __launch_bounds__(256) void rope_init(float2* __restrict__ T) {
    int i = blockIdx.x * 256 + threadIdx.x;   // [0, 65536)
    int s = i >> 5, tt = i & 31;
    float inv = exp2f(-(float)tt * (13.287712379549449f / 32.0f));
    float ang = (float)s * inv;
    T[i] = make_float2(cosf(ang), sinf(ang));
}

// ---------------------------------------------------------------------------
// QKV GEMM, single-pass fp16 MFMA, m97 2-barrier K-loop. 128x128, BK=64.
// XCD-swizzled grid (768 = 8 XCD x 96).
// q/k epilogue: R3-GREEN per-element form — register RoPE (pair partner is
// the adjacent lane via shfl_xor) + table lookup, direct global stores.
// NO post-K-loop LDS reuse in q/k blocks (the R4 fp32-LDS epilogue is the
// prime suspect for the timed-graph race; R3's form was equal-speed).
// v stored TRANSPOSED bf16 [B,H,HD,S'] with keys PERMUTED within each
// 64-group: key'(j) = (j&32) + ((j>>2)&3)*8 + ((j>>4)&1)*4 + (j&3) so attn's
// swapped-QK P registers are already the PV A-fragment.
// ---------------------------------------------------------------------------
__global__ __launch_bounds__(256) void gemm_qkv_f16(const ushort_t* __restrict__ Xh,
                                                    const ushort_t* __restrict__ Wh,
                                                    const float2* __restrict__ tab,
                                                    ushort_t* __restrict__ qb,
                                                    ushort_t* __restrict__ kb,
                                                    ushort_t* __restrict__ vtb) {
    __shared__ ushort_t SH[2][128 * 64];
    ushort_t* Ah = SH[0];
    ushort_t* Bh = SH[1];
    const int t = threadIdx.x;
    const int w = t >> 6, ln = t & 63;
    const int lane16 = ln & 15, quad = ln >> 4;
    const int wm = w >> 1, wn = w & 1;
    // bijective XCD swizzle: consecutive wgid share n0 (W-strip L2-hot)
    const int bid  = blockIdx.y * 24 + blockIdx.x;      // 0..767
    const int wgid = (bid & 7) * 96 + (bid >> 3);
    const int m0 = (wgid & 31) * 128;
    const int n0 = (wgid >> 5) * 128;
    const int c = n0 >> 10;               // 0=q 1=k 2=v (uniform per block)
    const int srow8 = ln >> 3;
    const int schunk = (ln & 7) ^ srow8;

    f32x4 acc[4][4];
    #pragma unroll
    for (int i = 0; i < 4; ++i)
        #pragma unroll
        for (int j = 0; j < 4; ++j) acc[i][j] = (f32x4){0.f, 0.f, 0.f, 0.f};

    for (int k0 = 0; k0 < D_; k0 += 64) {
        __syncthreads();
        #pragma unroll
        for (int i = 0; i < 4; ++i) {
            int rr = (i * 4 + w) * 8 + srow8;
            async16(Xh + (size_t)(m0 + rr) * D_ + k0 + schunk * 8, Ah + (i * 4 + w) * 512);
            async16(Wh + (size_t)(n0 + rr) * D_ + k0 + schunk * 8, Bh + (i * 4 + w) * 512);
        }
        __syncthreads();
        #pragma unroll
        for (int kc = 0; kc < 2; ++kc) {
            f16x8 af[4], bf[4];
            #pragma unroll
            for (int i = 0; i < 4; ++i) {
                int ra = wm * 64 + i * 16 + lane16;
                int ca = (kc * 4 + quad) ^ (ra & 7);
                af[i] = *(const f16x8*)&Ah[ra * 64 + ca * 8];
                int rb = wn * 64 + i * 16 + lane16;
                int cb = (kc * 4 + quad) ^ (rb & 7);
                bf[i] = *(const f16x8*)&Bh[rb * 64 + cb * 8];
            }
            #pragma unroll
            for (int i = 0; i < 4; ++i)
                #pragma unroll
                for (int j = 0; j < 4; ++j)
                    acc[i][j] = __builtin_amdgcn_mfma_f32_16x16x32_f16(af[i], bf[j], acc[i][j], 0, 0, 0);
        }
    }

    if (c < 2) {
        // --- q/k epilogue (R3-green): fused RoPE via table, in-register,
        // pair partner is the adjacent lane; direct scattered stores. ---
        const bool odd = (lane16 & 1) != 0;
        #pragma unroll
        for (int j = 0; j < 4; ++j) {
            int nb = n0 + wn * 64 + j * 16;
            int hh_ = (nb >> 6) & 15;
            int dcol = (nb & 63) + lane16;   // 0..63
            int tt = dcol >> 1;
            #pragma unroll
            for (int i = 0; i < 4; ++i)
                #pragma unroll
                for (int r = 0; r < 4; ++r) {
                    int m = m0 + wm * 64 + i * 16 + quad * 4 + r;
                    int b = m >> 11, s = m & (S_ - 1);
                    float val = acc[i][j][r];
                    float part = __shfl_xor(val, 1, 64);
                    float2 cs2 = tab[s * 32 + tt];
                    float cs = cs2.x, sn = cs2.y;
                    float x1 = odd ? part : val;
                    float x2 = odd ? val : part;
                    float res = odd ? fmaf(x1, sn, x2 * cs) : fmaf(x1, cs, -x2 * sn);
                    size_t idx = ((size_t)((b * H_ + hh_) * S_ + s)) * HD_ + dcol;
                    if (c == 0) qb[idx] = f2h(res * QSCALE);   // fold 1/sqrt(hd)*log2e
                    else        kb[idx] = f2h(res);
                }
        }
    } else {
        // v: transpose 128x128 tile through LDS with in-group key permutation
        // key-local j = i*16 + quad*4 + r  ->  pos = (i>>1)*32 + quad*8 + (i&1)*4 + r
        __syncthreads();                       // all waves done with K-loop LDS
        ushort_t* T = &SH[0][0];               // 128*128 shorts = 32 KB
        #pragma unroll
        for (int j = 0; j < 4; ++j) {
            int dl = wn * 64 + j * 16 + lane16;      // dcol_local 0..127
            int sw = lane16 << 3;                    // xor-swizzle bits 3..6
            #pragma unroll
            for (int i = 0; i < 4; ++i) {
                s16x4 v4;
                #pragma unroll
                for (int r = 0; r < 4; ++r) v4[r] = f2bf(acc[i][j][r]);
                int pos = wm * 64 + (i >> 1) * 32 + quad * 8 + (i & 1) * 4;
                *(s16x4*)&T[dl * 128 + (pos ^ sw)] = v4;
            }
        }
        __syncthreads();
        const int bb = m0 >> 11, sg0 = m0 & (S_ - 1);
        const int ln2 = ln * 2;
        #pragma unroll
        for (int it = 0; it < 32; ++it) {
            int row = it * 4 + w;                     // dcol_local 0..127
            int ng = n0 + row;
            int hh_ = (ng >> 6) & 15;
            int dg = ng & 63;
            unsigned int val = *(const unsigned int*)&T[row * 128 + (ln2 ^ ((row & 15) << 3))];
            size_t idxT = ((size_t)(bb * H_ + hh_) * HD_ + dg) * S_ + sg0 + ln2;
            *(unsigned int*)(vtb + idxT) = val;       // 256B/wave, coalesced
        }
    }
}

// ---------------------------------------------------------------------------
// O-projection, fp16 MFMA. BM=64 x BN=128 (512 blocks = 2/CU), BK=64,
// proven 2-barrier loop, XCD-swizzled grid (512 = 8 x 64). R7-green bytes.
// ---------------------------------------------------------------------------
__global__ __launch_bounds__(256) void gemm_out_f16(const ushort_t* __restrict__ Ag,
                                                    const ushort_t* __restrict__ Wg,
                                                    float* __restrict__ C) {
    __shared__ ushort_t As[64 * 64];
    __shared__ ushort_t Bs[128 * 64];
    const int t = threadIdx.x;
    const int w = t >> 6, ln = t & 63;
    const int lane16 = ln & 15, quad = ln >> 4;
    const int bid  = blockIdx.y * 8 + blockIdx.x;   // launched dim3(8,64)
    const int wgid = (bid & 7) * 64 + (bid >> 3);
    const int m0 = (wgid & 63) * 64;
    const int n0 = (wgid >> 6) * 128;
    const int srow8 = ln >> 3;
    const int schunk = (ln & 7) ^ srow8;
    f32x4 acc[4][2];
    #pragma unroll
    for (int i = 0; i < 4; ++i)
        #pragma unroll
        for (int j = 0; j < 2; ++j) acc[i][j] = (f32x4){0.f, 0.f, 0.f, 0.f};
    for (int k0 = 0; k0 < D_; k0 += 64) {
        __syncthreads();
        #pragma unroll
        for (int i = 0; i < 2; ++i) {
            int rr = (i * 4 + w) * 8 + srow8;
            async16(Ag + (size_t)(m0 + rr) * D_ + k0 + schunk * 8, As + (i * 4 + w) * 512);
        }
        #pragma unroll
        for (int i = 0; i < 4; ++i) {
            int rr = (i * 4 + w) * 8 + srow8;
            async16(Wg + (size_t)(n0 + rr) * D_ + k0 + schunk * 8, Bs + (i * 4 + w) * 512);
        }
        __syncthreads();
        #pragma unroll
        for (int kc = 0; kc < 2; ++kc) {
            f16x8 af[4], bf[2];
            #pragma unroll
            for (int i = 0; i < 4; ++i) {
                int ra = i * 16 + lane16;
                int ca = (kc * 4 + quad) ^ (ra & 7);
                af[i] = *(const f16x8*)&As[ra * 64 + ca * 8];
            }
            #pragma unroll
            for (int j = 0; j < 2; ++j) {
                int rb = w * 32 + j * 16 + lane16;
                int cb = (kc * 4 + quad) ^ (rb & 7);
                bf[j] = *(const f16x8*)&Bs[rb * 64 + cb * 8];
            }
            #pragma unroll
            for (int i = 0; i < 4; ++i)
                #pragma unroll
                for (int j = 0; j < 2; ++j)
                    acc[i][j] = __builtin_amdgcn_mfma_f32_16x16x32_f16(af[i], bf[j], acc[i][j], 0, 0, 0);
        }
    }
    #pragma unroll
    for (int i = 0; i < 4; ++i)
        #pragma unroll
        for (int j = 0; j < 2; ++j)
            #pragma unroll
            for (int r = 0; r < 4; ++r) {
                int m = m0 + i * 16 + quad * 4 + r;
                int n = n0 + w * 32 + j * 16 + lane16;
                C[(size_t)m * D_ + n] = acc[i][j][r];
            }
}

// ---------------------------------------------------------------------------
// MFMA flash attention. Complementary q-tile pairs {z, 31-z}: constant 33
// key-tiles/block => zero tail. Grid 512, bh = bx&31 (XCD-local K/V).
// SWAPPED QK^T: mfma(K,Q) puts P[q=lane16][key] lane-local; the key
// permutation (baked into vtb's column order) makes those registers exactly
// the PV A-fragment — P never touches LDS. Pack via v_cvt_pk_bf16_f32.
// Fixed-base softmax in exp2 units (q pre-scaled by log2e). R7-green bytes.
// ---------------------------------------------------------------------------
__device__ __forceinline__ void proc_tile(const f16x8* bq, f32x4* Of, float& l_,
                                          const ushort_t* Kc, const ushort_t* Vc,
                                          int j0, int qw0, int lane16, int quad,
                                          bool diag) {
    // swapped scores: D[key][q] — A = K rows (from LDS), B = Q (registers)
    f32x4 Sf[4];
    __builtin_amdgcn_s_setprio(1);
    #pragma unroll
    for (int nt = 0; nt < 4; ++nt) {
        int rk = nt * 16 + lane16;
        f16x8 ak0 = *(const f16x8*)&Kc[rk * 64 + ((quad)     ^ (rk & 7)) * 8];
        f16x8 ak1 = *(const f16x8*)&Kc[rk * 64 + ((4 + quad) ^ (rk & 7)) * 8];
        f32x4 zz = (f32x4){0.f, 0.f, 0.f, 0.f};
        zz = __builtin_amdgcn_mfma_f32_16x16x32_f16(ak0, bq[0], zz, 0, 0, 0);
        zz = __builtin_amdgcn_mfma_f32_16x16x32_f16(ak1, bq[1], zz, 0, 0, 0);
        Sf[nt] = zz;
    }
    __builtin_amdgcn_s_setprio(0);

    if (diag) {   // causal mask: row = key, col = q
        int qq = qw0 + lane16;
        #pragma unroll
        for (int nt = 0; nt < 4; ++nt)
            #pragma unroll
            for (int r = 0; r < 4; ++r) {
                int key = j0 + nt * 16 + quad * 4 + r;
                if (key > qq) Sf[nt][r] = -1e30f;
            }
    }

    // fixed-base exp2; this lane's 16 P values are for q = lane16
    float p[4][4];
    #pragma unroll
    for (int nt = 0; nt < 4; ++nt)
        #pragma unroll
        for (int r = 0; r < 4; ++r)
            p[nt][r] = __builtin_amdgcn_exp2f(Sf[nt][r] - EXPOFF);
    #pragma unroll
    for (int nt = 0; nt < 4; ++nt)
        l_ += (p[nt][0] + p[nt][1]) + (p[nt][2] + p[nt][3]);

    // pack to PV A-fragments in-register: ap[kk] elem e = p[2kk+(e>>2)][e&3]
    union { bf16x8 v; unsigned u[4]; } ap0, ap1;
    asm("v_cvt_pk_bf16_f32 %0, %1, %2" : "=v"(ap0.u[0]) : "v"(p[0][0]), "v"(p[0][1]));
    asm("v_cvt_pk_bf16_f32 %0, %1, %2" : "=v"(ap0.u[1]) : "v"(p[0][2]), "v"(p[0][3]));
    asm("v_cvt_pk_bf16_f32 %0, %1, %2" : "=v"(ap0.u[2]) : "v"(p[1][0]), "v"(p[1][1]));
    asm("v_cvt_pk_bf16_f32 %0, %1, %2" : "=v"(ap0.u[3]) : "v"(p[1][2]), "v"(p[1][3]));
    asm("v_cvt_pk_bf16_f32 %0, %1, %2" : "=v"(ap1.u[0]) : "v"(p[2][0]), "v"(p[2][1]));
    asm("v_cvt_pk_bf16_f32 %0, %1, %2" : "=v"(ap1.u[1]) : "v"(p[2][2]), "v"(p[2][3]));
    asm("v_cvt_pk_bf16_f32 %0, %1, %2" : "=v"(ap1.u[2]) : "v"(p[3][0]), "v"(p[3][1]));
    asm("v_cvt_pk_bf16_f32 %0, %1, %2" : "=v"(ap1.u[3]) : "v"(p[3][2]), "v"(p[3][3]));

    // PV, bf16; V columns stored in key' order (matches ap fragments)
    __builtin_amdgcn_s_setprio(1);
    #pragma unroll
    for (int nt = 0; nt < 4; ++nt) {
        int rd = nt * 16 + lane16;
        bf16x8 bv0 = *(const bf16x8*)&Vc[rd * 64 + ((quad)     ^ (rd & 7)) * 8];
        bf16x8 bv1 = *(const bf16x8*)&Vc[rd * 64 + ((4 + quad) ^ (rd & 7)) * 8];
        Of[nt] = __builtin_amdgcn_mfma_f32_16x16x32_bf16(ap0.v, bv0, Of[nt], 0, 0, 0);
        Of[nt] = __builtin_amdgcn_mfma_f32_16x16x32_bf16(ap1.v, bv1, Of[nt], 0, 0, 0);
    }
    __builtin_amdgcn_s_setprio(0);
}

__global__ __launch_bounds__(256) void attn_mfma(const ushort_t* __restrict__ qbuf,
                                                 const ushort_t* __restrict__ kbuf,
                                                 const ushort_t* __restrict__ vtb,
                                                 ushort_t* __restrict__ att) {
    __shared__ ushort_t Kl[2][64 * 64];
    __shared__ ushort_t Vt[2][64 * 64];

    const int bx = blockIdx.x;
    const int bh = bx & 31;            // same (b,h) => same XCD (bx%8 uniform)
    const int z  = (bx >> 5) & 15;
    const int qtA = z, qtB = 31 - z;   // complementary pair: 33 tiles total
    const int qA = qtA * 64, qB = qtB * 64;
    const int t  = threadIdx.x;
    const int w  = t >> 6;
    const int ln = t & 63;
    const int lane16 = ln & 15;
    const int quad   = ln >> 4;
    const int b = bh >> 4, h = bh & 15;
    const int srow8 = ln >> 3;
    const int schunk = (ln & 7) ^ srow8;

    const ushort_t* qg  = qbuf + (size_t)bh * S_ * HD_;
    const ushort_t* kg  = kbuf + (size_t)bh * S_ * HD_;
    const ushort_t* vtg = vtb  + (size_t)bh * HD_ * S_;   // [HD][S'] (permuted)

    // Q fragments (used as MFMA B-operand), fp16
    f16x8 bqA[2], bqB[2];
    {
        size_t ro = (size_t)(qA + w * 16 + lane16) * HD_;
        bqA[0] = *(const f16x8*)(qg + ro + quad * 8);
        bqA[1] = *(const f16x8*)(qg + ro + 32 + quad * 8);
    }
    {
        size_t ro = (size_t)(qB + w * 16 + lane16) * HD_;
        bqB[0] = *(const f16x8*)(qg + ro + quad * 8);
        bqB[1] = *(const f16x8*)(qg + ro + 32 + quad * 8);
    }

    float lA = 0.f, lB = 0.f;          // partial l for q = lane16 (per tile-set)
    f32x4 OA[4], OB[4];
    #pragma unroll
    for (int nt = 0; nt < 4; ++nt) {
        OA[nt] = (f32x4){0.f, 0.f, 0.f, 0.f};
        OB[nt] = (f32x4){0.f, 0.f, 0.f, 0.f};
    }

    #define STAGE_TILE(JT, BUFI)                                                   \
        {                                                                          \
            int j0_ = (JT) * 64;                                                   \
            async16(kg + (size_t)(j0_ + w * 8 + srow8) * HD_ + schunk * 8,         \
                    &Kl[BUFI][(w * 8) * 64]);                                      \
            async16(kg + (size_t)(j0_ + 32 + w * 8 + srow8) * HD_ + schunk * 8,    \
                    &Kl[BUFI][(32 + w * 8) * 64]);                                 \
            async16(vtg + (size_t)(w * 8 + srow8) * S_ + j0_ + schunk * 8,         \
                    &Vt[BUFI][(w * 8) * 64]);                                      \
            async16(vtg + (size_t)(32 + w * 8 + srow8) * S_ + j0_ + schunk * 8,    \
                    &Vt[BUFI][(32 + w * 8) * 64]);                                 \
        }

    STAGE_TILE(0, 0)

    const int qwA = qA + w * 16, qwB = qB + w * 16;

    for (int jt = 0; jt <= qtB; ++jt) {
        const int j0 = jt * 64;
        const int cur = jt & 1;
        __syncthreads();                       // drains staging of tile jt
        if (jt < qtB) STAGE_TILE(jt + 1, cur ^ 1)   // overlaps with compute below

        proc_tile(bqB, OB, lB, &Kl[cur][0], &Vt[cur][0], j0, qwB, lane16, quad,
                  jt == qtB);
        if (jt <= qtA)
            proc_tile(bqA, OA, lA, &Kl[cur][0], &Vt[cur][0], j0, qwA, lane16, quad,
                      jt == qtA);
    }
    #undef STAGE_TILE

    // epilogue: reduce l across quads (lanes sharing lane16), fetch per-row via
    // shfl, store fp16. O layout: row q = quad*4+r, col d = nt*16+lane16.
    float LA = lA, LB = lB;
    LA += __shfl_xor(LA, 16, 64); LA += __shfl_xor(LA, 32, 64);
    LB += __shfl_xor(LB, 16, 64); LB += __shfl_xor(LB, 32, 64);
    #pragma unroll
    for (int r = 0; r < 4; ++r) {
        float lv = __shfl(LA, quad * 4 + r, 64);
        float inv_l = 1.0f / fmaxf(lv, 1e-30f);
        int s = qA + w * 16 + quad * 4 + r;
        ushort_t* dst = att + ((size_t)(b * S_ + s)) * D_ + h * HD_;
        #pragma unroll
        for (int nt = 0; nt < 4; ++nt)
            dst[nt * 16 + lane16] = f2h(OA[nt][r] * inv_l);
    }
    #pragma unroll
    for (int r = 0; r < 4; ++r) {
        float lv = __shfl(LB, quad * 4 + r, 64);
        float inv_l = 1.0f / fmaxf(lv, 1e-30f);
        int s = qB + w * 16 + quad * 4 + r;
        ushort_t* dst = att + ((size_t)(b * S_ + s)) * D_ + h * HD_;
        #pragma unroll
        for (int nt = 0; nt < 4; ++nt)
            dst[nt * 16 + lane16] = f2h(OB[nt][r] * inv_l);
    }
}

// ---------------------------------------------------------------------------
extern "C" void kernel_launch(void* const* d_in, const int* in_sizes, int n_in,
                              void* d_out, int out_size, void* d_ws, size_t ws_size,
                              hipStream_t stream) {
    const float* X    = (const float*)d_in[0];   // [B,S,D] fp32
    const float* Wqkv = (const float*)d_in[2];   // [3D,D] fp32
    const float* Wo   = (const float*)d_in[3];   // [D,D] fp32
    float* out = (float*)d_out;

    ushort_t* ws = (ushort_t*)d_ws;
    const size_t QS = (size_t)B_ * H_ * S_ * HD_;   // 4,194,304 elems
    ushort_t* qb   = ws;                            // QS  fp16
    ushort_t* kbuf = qb   + QS;                     // QS  fp16
    ushort_t* vtbuf= kbuf + QS;                     // QS  bf16 [B,H,HD,S'] (perm)
    ushort_t* Woh  = vtbuf + QS;                    // 1M  fp16 (rope table aliases
                                                    //     this region during qkv)
    ushort_t* Xh   = Woh  + (size_t)D_ * D_;        // 4M  fp16 (attb aliases)
    ushort_t* Wh   = Xh   + (size_t)M_ * D_;        // 3M  fp16
    ushort_t* attb = Xh;                            // alias: Xh dead after gemm_qkv
    float2* rope   = (float2*)Woh;                  // 512 KB, dead after gemm_qkv

    cvt_f16<<<2048, 256, 0, stream>>>(X,    Xh,  (M_ * D_) / 8);
    cvt_f16<<<1536, 256, 0, stream>>>(Wqkv, Wh,  (NE_ * D_) / 8);
    rope_init<<<256, 256, 0, stream>>>(rope);

    gemm_qkv_f16<<<dim3(NE_ / 128, M_ / 128), 256, 0, stream>>>(Xh, Wh, rope, qb, kbuf, vtbuf);

    // Wo conversion AFTER gemm_qkv: Woh region holds the rope table until here
    cvt_f16<<<512, 256, 0, stream>>>(Wo, Woh, (D_ * D_) / 8);

    attn_mfma<<<B_ * H_ * (S_ / 128), 256, 0, stream>>>(qb, kbuf, vtbuf, attb);
    gemm_out_f16<<<dim3(D_ / 128, M_ / 64), 256, 0, stream>>>(attb, Woh, out);
}

// Round 14
// 191.968 us; speedup vs baseline: 1.0017x; 1.0017x over previous
//
#include <hip/hip_runtime.h>
#include <hip/hip_bf16.h>
#include <math.h>

// Problem constants (fixed by setup_inputs)
#define B_  2
#define S_  2048
#define D_  1024
#define H_  16
#define HD_ 64
#define NE_ 3072   // 3*D
#define M_  4096   // B*S

typedef unsigned short ushort_t;
typedef __attribute__((ext_vector_type(8))) short bf16x8;
typedef __attribute__((ext_vector_type(8))) _Float16 f16x8;
typedef __attribute__((ext_vector_type(4))) float f32x4;
typedef __attribute__((ext_vector_type(4))) short s16x4;

// log2(e) folded into q-scale; softmax base folded into exp2 offset
#define QSCALE 0.18033688011112042f      // 0.125 * log2(e)
#define EXPOFF 46.166240909416444f       // 32 * log2(e)

__device__ __forceinline__ short f2bf(float f) {
    union { float f; unsigned u; } v; v.f = f;
    unsigned u = v.u;
    u += 0x7fffu + ((u >> 16) & 1u);   // round-to-nearest-even
    return (short)(u >> 16);
}
__device__ __forceinline__ ushort_t f2h(float f) {
    union { _Float16 h; ushort_t u; } v;
    v.h = (_Float16)f;                 // v_cvt_f16_f32, RTE
    return v.u;
}

// async global->LDS, 16B per lane; LDS dest = wave-uniform base + lane*16
__device__ __forceinline__ void async16(const ushort_t* g, ushort_t* l) {
    __builtin_amdgcn_global_load_lds(
        (const __attribute__((address_space(1))) void*)g,
        (__attribute__((address_space(3))) void*)l,
        16, 0, 0);
}

// ---------------------------------------------------------------------------
// fp32 -> fp16 conversion (8 elems/thread) — X, Wqkv, Wo
// ---------------------------------------------------------------------------
__global__ __launch_bounds__(256) void cvt_f16(const float* __restrict__ s,
                                               ushort_t* __restrict__ d, int n8) {
    int i = blockIdx.x * 256 + threadIdx.x;
    if (i >= n8) return;
    const float4* sp = (const float4*)s;
    float4 a = sp[2 * (size_t)i], b = sp[2 * (size_t)i + 1];
    f16x8 o;
    o[0] = (_Float16)a.x; o[1] = (_Float16)a.y; o[2] = (_Float16)a.z; o[3] = (_Float16)a.w;
    o[4] = (_Float16)b.x; o[5] = (_Float16)b.y; o[6] = (_Float16)b.z; o[7] = (_Float16)b.w;
    *(f16x8*)(d + 8 * (size_t)i) = o;
}

// ---------------------------------------------------------------------------
// RoPE cos/sin table: tab[s*32 + tt] = (cos(s*theta^(-tt/32)), sin(...)).
// 512 KB, one-shot, L2-resident during gemm_qkv.
// ---------------------------------------------------------------------------
__global__ __launch_bounds__(256) void rope_init(float2* __restrict__ T) {
    int i = blockIdx.x * 256 + threadIdx.x;   // [0, 65536)
    int s = i >> 5, tt = i & 31;
    float inv = exp2f(-(float)tt * (13.287712379549449f / 32.0f));
    float ang = (float)s * inv;
    T[i] = make_float2(cosf(ang), sinf(ang));
}

// ---------------------------------------------------------------------------
// QKV GEMM, single-pass fp16 MFMA, m97 2-barrier K-loop. 128x128, BK=64.
// XCD-swizzled grid (768 = 8 XCD x 96).
// q/k epilogue: R3/R12-green per-element form — register RoPE (pair partner
// is the adjacent lane via shfl_xor) + table lookup, direct global stores.
// NO post-K-loop LDS reuse in q/k blocks.
// v stored TRANSPOSED bf16 [B,H,HD,S'] with keys PERMUTED within each
// 64-group: key'(j) = (j&32) + ((j>>2)&3)*8 + ((j>>4)&1)*4 + (j&3) so attn's
// swapped-QK P registers are already the PV A-fragment.
// R12-GREEN BYTES — passed direct absmax + timed-graph + rocprof replays.
// ---------------------------------------------------------------------------
__global__ __launch_bounds__(256) void gemm_qkv_f16(const ushort_t* __restrict__ Xh,
                                                    const ushort_t* __restrict__ Wh,
                                                    const float2* __restrict__ tab,
                                                    ushort_t* __restrict__ qb,
                                                    ushort_t* __restrict__ kb,
                                                    ushort_t* __restrict__ vtb) {
    __shared__ ushort_t SH[2][128 * 64];
    ushort_t* Ah = SH[0];
    ushort_t* Bh = SH[1];
    const int t = threadIdx.x;
    const int w = t >> 6, ln = t & 63;
    const int lane16 = ln & 15, quad = ln >> 4;
    const int wm = w >> 1, wn = w & 1;
    // bijective XCD swizzle: consecutive wgid share n0 (W-strip L2-hot)
    const int bid  = blockIdx.y * 24 + blockIdx.x;      // 0..767
    const int wgid = (bid & 7) * 96 + (bid >> 3);
    const int m0 = (wgid & 31) * 128;
    const int n0 = (wgid >> 5) * 128;
    const int c = n0 >> 10;               // 0=q 1=k 2=v (uniform per block)
    const int srow8 = ln >> 3;
    const int schunk = (ln & 7) ^ srow8;

    f32x4 acc[4][4];
    #pragma unroll
    for (int i = 0; i < 4; ++i)
        #pragma unroll
        for (int j = 0; j < 4; ++j) acc[i][j] = (f32x4){0.f, 0.f, 0.f, 0.f};

    for (int k0 = 0; k0 < D_; k0 += 64) {
        __syncthreads();
        #pragma unroll
        for (int i = 0; i < 4; ++i) {
            int rr = (i * 4 + w) * 8 + srow8;
            async16(Xh + (size_t)(m0 + rr) * D_ + k0 + schunk * 8, Ah + (i * 4 + w) * 512);
            async16(Wh + (size_t)(n0 + rr) * D_ + k0 + schunk * 8, Bh + (i * 4 + w) * 512);
        }
        __syncthreads();
        #pragma unroll
        for (int kc = 0; kc < 2; ++kc) {
            f16x8 af[4], bf[4];
            #pragma unroll
            for (int i = 0; i < 4; ++i) {
                int ra = wm * 64 + i * 16 + lane16;
                int ca = (kc * 4 + quad) ^ (ra & 7);
                af[i] = *(const f16x8*)&Ah[ra * 64 + ca * 8];
                int rb = wn * 64 + i * 16 + lane16;
                int cb = (kc * 4 + quad) ^ (rb & 7);
                bf[i] = *(const f16x8*)&Bh[rb * 64 + cb * 8];
            }
            #pragma unroll
            for (int i = 0; i < 4; ++i)
                #pragma unroll
                for (int j = 0; j < 4; ++j)
                    acc[i][j] = __builtin_amdgcn_mfma_f32_16x16x32_f16(af[i], bf[j], acc[i][j], 0, 0, 0);
        }
    }

    if (c < 2) {
        // --- q/k epilogue (R3-green): fused RoPE via table, in-register,
        // pair partner is the adjacent lane; direct scattered stores. ---
        const bool odd = (lane16 & 1) != 0;
        #pragma unroll
        for (int j = 0; j < 4; ++j) {
            int nb = n0 + wn * 64 + j * 16;
            int hh_ = (nb >> 6) & 15;
            int dcol = (nb & 63) + lane16;   // 0..63
            int tt = dcol >> 1;
            #pragma unroll
            for (int i = 0; i < 4; ++i)
                #pragma unroll
                for (int r = 0; r < 4; ++r) {
                    int m = m0 + wm * 64 + i * 16 + quad * 4 + r;
                    int b = m >> 11, s = m & (S_ - 1);
                    float val = acc[i][j][r];
                    float part = __shfl_xor(val, 1, 64);
                    float2 cs2 = tab[s * 32 + tt];
                    float cs = cs2.x, sn = cs2.y;
                    float x1 = odd ? part : val;
                    float x2 = odd ? val : part;
                    float res = odd ? fmaf(x1, sn, x2 * cs) : fmaf(x1, cs, -x2 * sn);
                    size_t idx = ((size_t)((b * H_ + hh_) * S_ + s)) * HD_ + dcol;
                    if (c == 0) qb[idx] = f2h(res * QSCALE);   // fold 1/sqrt(hd)*log2e
                    else        kb[idx] = f2h(res);
                }
        }
    } else {
        // v: transpose 128x128 tile through LDS with in-group key permutation
        // key-local j = i*16 + quad*4 + r  ->  pos = (i>>1)*32 + quad*8 + (i&1)*4 + r
        __syncthreads();                       // all waves done with K-loop LDS
        ushort_t* T = &SH[0][0];               // 128*128 shorts = 32 KB
        #pragma unroll
        for (int j = 0; j < 4; ++j) {
            int dl = wn * 64 + j * 16 + lane16;      // dcol_local 0..127
            int sw = lane16 << 3;                    // xor-swizzle bits 3..6
            #pragma unroll
            for (int i = 0; i < 4; ++i) {
                s16x4 v4;
                #pragma unroll
                for (int r = 0; r < 4; ++r) v4[r] = f2bf(acc[i][j][r]);
                int pos = wm * 64 + (i >> 1) * 32 + quad * 8 + (i & 1) * 4;
                *(s16x4*)&T[dl * 128 + (pos ^ sw)] = v4;
            }
        }
        __syncthreads();
        const int bb = m0 >> 11, sg0 = m0 & (S_ - 1);
        const int ln2 = ln * 2;
        #pragma unroll
        for (int it = 0; it < 32; ++it) {
            int row = it * 4 + w;                     // dcol_local 0..127
            int ng = n0 + row;
            int hh_ = (ng >> 6) & 15;
            int dg = ng & 63;
            unsigned int val = *(const unsigned int*)&T[row * 128 + (ln2 ^ ((row & 15) << 3))];
            size_t idxT = ((size_t)(bb * H_ + hh_) * HD_ + dg) * S_ + sg0 + ln2;
            *(unsigned int*)(vtb + idxT) = val;       // 256B/wave, coalesced
        }
    }
}

// ---------------------------------------------------------------------------
// O-projection, fp16 MFMA. BM=64 x BN=128 (512 blocks = 2/CU), BK=64,
// proven 2-barrier loop, XCD-swizzled grid (512 = 8 x 64). R12 bytes.
// ---------------------------------------------------------------------------
__global__ __launch_bounds__(256) void gemm_out_f16(const ushort_t* __restrict__ Ag,
                                                    const ushort_t* __restrict__ Wg,
                                                    float* __restrict__ C) {
    __shared__ ushort_t As[64 * 64];
    __shared__ ushort_t Bs[128 * 64];
    const int t = threadIdx.x;
    const int w = t >> 6, ln = t & 63;
    const int lane16 = ln & 15, quad = ln >> 4;
    const int bid  = blockIdx.y * 8 + blockIdx.x;   // launched dim3(8,64)
    const int wgid = (bid & 7) * 64 + (bid >> 3);
    const int m0 = (wgid & 63) * 64;
    const int n0 = (wgid >> 6) * 128;
    const int srow8 = ln >> 3;
    const int schunk = (ln & 7) ^ srow8;
    f32x4 acc[4][2];
    #pragma unroll
    for (int i = 0; i < 4; ++i)
        #pragma unroll
        for (int j = 0; j < 2; ++j) acc[i][j] = (f32x4){0.f, 0.f, 0.f, 0.f};
    for (int k0 = 0; k0 < D_; k0 += 64) {
        __syncthreads();
        #pragma unroll
        for (int i = 0; i < 2; ++i) {
            int rr = (i * 4 + w) * 8 + srow8;
            async16(Ag + (size_t)(m0 + rr) * D_ + k0 + schunk * 8, As + (i * 4 + w) * 512);
        }
        #pragma unroll
        for (int i = 0; i < 4; ++i) {
            int rr = (i * 4 + w) * 8 + srow8;
            async16(Wg + (size_t)(n0 + rr) * D_ + k0 + schunk * 8, Bs + (i * 4 + w) * 512);
        }
        __syncthreads();
        #pragma unroll
        for (int kc = 0; kc < 2; ++kc) {
            f16x8 af[4], bf[2];
            #pragma unroll
            for (int i = 0; i < 4; ++i) {
                int ra = i * 16 + lane16;
                int ca = (kc * 4 + quad) ^ (ra & 7);
                af[i] = *(const f16x8*)&As[ra * 64 + ca * 8];
            }
            #pragma unroll
            for (int j = 0; j < 2; ++j) {
                int rb = w * 32 + j * 16 + lane16;
                int cb = (kc * 4 + quad) ^ (rb & 7);
                bf[j] = *(const f16x8*)&Bs[rb * 64 + cb * 8];
            }
            #pragma unroll
            for (int i = 0; i < 4; ++i)
                #pragma unroll
                for (int j = 0; j < 2; ++j)
                    acc[i][j] = __builtin_amdgcn_mfma_f32_16x16x32_f16(af[i], bf[j], acc[i][j], 0, 0, 0);
        }
    }
    #pragma unroll
    for (int i = 0; i < 4; ++i)
        #pragma unroll
        for (int j = 0; j < 2; ++j)
            #pragma unroll
            for (int r = 0; r < 4; ++r) {
                int m = m0 + i * 16 + quad * 4 + r;
                int n = n0 + w * 32 + j * 16 + lane16;
                C[(size_t)m * D_ + n] = acc[i][j][r];
            }
}

// ---------------------------------------------------------------------------
// MFMA flash attention. Complementary q-tile pairs {z, 31-z}: constant 33
// key-tiles/block => zero tail. Grid 512, bh = bx&31 (XCD-local K/V).
// SWAPPED QK^T: mfma(K,Q) puts P[q=lane16][key] lane-local; the key
// permutation (baked into vtb's column order) makes those registers exactly
// the PV A-fragment — P never touches LDS. Pack via v_cvt_pk_bf16_f32.
// Fixed-base softmax in exp2 units (q pre-scaled by log2e). R12 bytes.
// ---------------------------------------------------------------------------
__device__ __forceinline__ void proc_tile(const f16x8* bq, f32x4* Of, float& l_,
                                          const ushort_t* Kc, const ushort_t* Vc,
                                          int j0, int qw0, int lane16, int quad,
                                          bool diag) {
    // swapped scores: D[key][q] — A = K rows (from LDS), B = Q (registers)
    f32x4 Sf[4];
    __builtin_amdgcn_s_setprio(1);
    #pragma unroll
    for (int nt = 0; nt < 4; ++nt) {
        int rk = nt * 16 + lane16;
        f16x8 ak0 = *(const f16x8*)&Kc[rk * 64 + ((quad)     ^ (rk & 7)) * 8];
        f16x8 ak1 = *(const f16x8*)&Kc[rk * 64 + ((4 + quad) ^ (rk & 7)) * 8];
        f32x4 zz = (f32x4){0.f, 0.f, 0.f, 0.f};
        zz = __builtin_amdgcn_mfma_f32_16x16x32_f16(ak0, bq[0], zz, 0, 0, 0);
        zz = __builtin_amdgcn_mfma_f32_16x16x32_f16(ak1, bq[1], zz, 0, 0, 0);
        Sf[nt] = zz;
    }
    __builtin_amdgcn_s_setprio(0);

    if (diag) {   // causal mask: row = key, col = q
        int qq = qw0 + lane16;
        #pragma unroll
        for (int nt = 0; nt < 4; ++nt)
            #pragma unroll
            for (int r = 0; r < 4; ++r) {
                int key = j0 + nt * 16 + quad * 4 + r;
                if (key > qq) Sf[nt][r] = -1e30f;
            }
    }

    // fixed-base exp2; this lane's 16 P values are for q = lane16
    float p[4][4];
    #pragma unroll
    for (int nt = 0; nt < 4; ++nt)
        #pragma unroll
        for (int r = 0; r < 4; ++r)
            p[nt][r] = __builtin_amdgcn_exp2f(Sf[nt][r] - EXPOFF);
    #pragma unroll
    for (int nt = 0; nt < 4; ++nt)
        l_ += (p[nt][0] + p[nt][1]) + (p[nt][2] + p[nt][3]);

    // pack to PV A-fragments in-register: ap[kk] elem e = p[2kk+(e>>2)][e&3]
    union { bf16x8 v; unsigned u[4]; } ap0, ap1;
    asm("v_cvt_pk_bf16_f32 %0, %1, %2" : "=v"(ap0.u[0]) : "v"(p[0][0]), "v"(p[0][1]));
    asm("v_cvt_pk_bf16_f32 %0, %1, %2" : "=v"(ap0.u[1]) : "v"(p[0][2]), "v"(p[0][3]));
    asm("v_cvt_pk_bf16_f32 %0, %1, %2" : "=v"(ap0.u[2]) : "v"(p[1][0]), "v"(p[1][1]));
    asm("v_cvt_pk_bf16_f32 %0, %1, %2" : "=v"(ap0.u[3]) : "v"(p[1][2]), "v"(p[1][3]));
    asm("v_cvt_pk_bf16_f32 %0, %1, %2" : "=v"(ap1.u[0]) : "v"(p[2][0]), "v"(p[2][1]));
    asm("v_cvt_pk_bf16_f32 %0, %1, %2" : "=v"(ap1.u[1]) : "v"(p[2][2]), "v"(p[2][3]));
    asm("v_cvt_pk_bf16_f32 %0, %1, %2" : "=v"(ap1.u[2]) : "v"(p[3][0]), "v"(p[3][1]));
    asm("v_cvt_pk_bf16_f32 %0, %1, %2" : "=v"(ap1.u[3]) : "v"(p[3][2]), "v"(p[3][3]));

    // PV, bf16; V columns stored in key' order (matches ap fragments)
    __builtin_amdgcn_s_setprio(1);
    #pragma unroll
    for (int nt = 0; nt < 4; ++nt) {
        int rd = nt * 16 + lane16;
        bf16x8 bv0 = *(const bf16x8*)&Vc[rd * 64 + ((quad)     ^ (rd & 7)) * 8];
        bf16x8 bv1 = *(const bf16x8*)&Vc[rd * 64 + ((4 + quad) ^ (rd & 7)) * 8];
        Of[nt] = __builtin_amdgcn_mfma_f32_16x16x32_bf16(ap0.v, bv0, Of[nt], 0, 0, 0);
        Of[nt] = __builtin_amdgcn_mfma_f32_16x16x32_bf16(ap1.v, bv1, Of[nt], 0, 0, 0);
    }
    __builtin_amdgcn_s_setprio(0);
}

__global__ __launch_bounds__(256) void attn_mfma(const ushort_t* __restrict__ qbuf,
                                                 const ushort_t* __restrict__ kbuf,
                                                 const ushort_t* __restrict__ vtb,
                                                 ushort_t* __restrict__ att) {
    __shared__ ushort_t Kl[2][64 * 64];
    __shared__ ushort_t Vt[2][64 * 64];

    const int bx = blockIdx.x;
    const int bh = bx & 31;            // same (b,h) => same XCD (bx%8 uniform)
    const int z  = (bx >> 5) & 15;
    const int qtA = z, qtB = 31 - z;   // complementary pair: 33 tiles total
    const int qA = qtA * 64, qB = qtB * 64;
    const int t  = threadIdx.x;
    const int w  = t >> 6;
    const int ln = t & 63;
    const int lane16 = ln & 15;
    const int quad   = ln >> 4;
    const int b = bh >> 4, h = bh & 15;
    const int srow8 = ln >> 3;
    const int schunk = (ln & 7) ^ srow8;

    const ushort_t* qg  = qbuf + (size_t)bh * S_ * HD_;
    const ushort_t* kg  = kbuf + (size_t)bh * S_ * HD_;
    const ushort_t* vtg = vtb  + (size_t)bh * HD_ * S_;   // [HD][S'] (permuted)

    // Q fragments (used as MFMA B-operand), fp16
    f16x8 bqA[2], bqB[2];
    {
        size_t ro = (size_t)(qA + w * 16 + lane16) * HD_;
        bqA[0] = *(const f16x8*)(qg + ro + quad * 8);
        bqA[1] = *(const f16x8*)(qg + ro + 32 + quad * 8);
    }
    {
        size_t ro = (size_t)(qB + w * 16 + lane16) * HD_;
        bqB[0] = *(const f16x8*)(qg + ro + quad * 8);
        bqB[1] = *(const f16x8*)(qg + ro + 32 + quad * 8);
    }

    float lA = 0.f, lB = 0.f;          // partial l for q = lane16 (per tile-set)
    f32x4 OA[4], OB[4];
    #pragma unroll
    for (int nt = 0; nt < 4; ++nt) {
        OA[nt] = (f32x4){0.f, 0.f, 0.f, 0.f};
        OB[nt] = (f32x4){0.f, 0.f, 0.f, 0.f};
    }

    #define STAGE_TILE(JT, BUFI)                                                   \
        {                                                                          \
            int j0_ = (JT) * 64;                                                   \
            async16(kg + (size_t)(j0_ + w * 8 + srow8) * HD_ + schunk * 8,         \
                    &Kl[BUFI][(w * 8) * 64]);                                      \
            async16(kg + (size_t)(j0_ + 32 + w * 8 + srow8) * HD_ + schunk * 8,    \
                    &Kl[BUFI][(32 + w * 8) * 64]);                                 \
            async16(vtg + (size_t)(w * 8 + srow8) * S_ + j0_ + schunk * 8,         \
                    &Vt[BUFI][(w * 8) * 64]);                                      \
            async16(vtg + (size_t)(32 + w * 8 + srow8) * S_ + j0_ + schunk * 8,    \
                    &Vt[BUFI][(32 + w * 8) * 64]);                                 \
        }

    STAGE_TILE(0, 0)

    const int qwA = qA + w * 16, qwB = qB + w * 16;

    for (int jt = 0; jt <= qtB; ++jt) {
        const int j0 = jt * 64;
        const int cur = jt & 1;
        __syncthreads();                       // drains staging of tile jt
        if (jt < qtB) STAGE_TILE(jt + 1, cur ^ 1)   // overlaps with compute below

        proc_tile(bqB, OB, lB, &Kl[cur][0], &Vt[cur][0], j0, qwB, lane16, quad,
                  jt == qtB);
        if (jt <= qtA)
            proc_tile(bqA, OA, lA, &Kl[cur][0], &Vt[cur][0], j0, qwA, lane16, quad,
                      jt == qtA);
    }
    #undef STAGE_TILE

    // epilogue: reduce l across quads (lanes sharing lane16), fetch per-row via
    // shfl, store fp16. O layout: row q = quad*4+r, col d = nt*16+lane16.
    float LA = lA, LB = lB;
    LA += __shfl_xor(LA, 16, 64); LA += __shfl_xor(LA, 32, 64);
    LB += __shfl_xor(LB, 16, 64); LB += __shfl_xor(LB, 32, 64);
    #pragma unroll
    for (int r = 0; r < 4; ++r) {
        float lv = __shfl(LA, quad * 4 + r, 64);
        float inv_l = 1.0f / fmaxf(lv, 1e-30f);
        int s = qA + w * 16 + quad * 4 + r;
        ushort_t* dst = att + ((size_t)(b * S_ + s)) * D_ + h * HD_;
        #pragma unroll
        for (int nt = 0; nt < 4; ++nt)
            dst[nt * 16 + lane16] = f2h(OA[nt][r] * inv_l);
    }
    #pragma unroll
    for (int r = 0; r < 4; ++r) {
        float lv = __shfl(LB, quad * 4 + r, 64);
        float inv_l = 1.0f / fmaxf(lv, 1e-30f);
        int s = qB + w * 16 + quad * 4 + r;
        ushort_t* dst = att + ((size_t)(b * S_ + s)) * D_ + h * HD_;
        #pragma unroll
        for (int nt = 0; nt < 4; ++nt)
            dst[nt * 16 + lane16] = f2h(OB[nt][r] * inv_l);
    }
}

// ---------------------------------------------------------------------------
extern "C" void kernel_launch(void* const* d_in, const int* in_sizes, int n_in,
                              void* d_out, int out_size, void* d_ws, size_t ws_size,
                              hipStream_t stream) {
    const float* X    = (const float*)d_in[0];   // [B,S,D] fp32
    const float* Wqkv = (const float*)d_in[2];   // [3D,D] fp32
    const float* Wo   = (const float*)d_in[3];   // [D,D] fp32
    float* out = (float*)d_out;

    ushort_t* ws = (ushort_t*)d_ws;
    const size_t QS = (size_t)B_ * H_ * S_ * HD_;   // 4,194,304 elems
    ushort_t* qb   = ws;                            // QS  fp16
    ushort_t* kbuf = qb   + QS;                     // QS  fp16
    ushort_t* vtbuf= kbuf + QS;                     // QS  bf16 [B,H,HD,S'] (perm)
    ushort_t* Woh  = vtbuf + QS;                    // 1M  fp16 (rope table aliases
                                                    //     this region during qkv)
    ushort_t* Xh   = Woh  + (size_t)D_ * D_;        // 4M  fp16 (attb aliases)
    ushort_t* Wh   = Xh   + (size_t)M_ * D_;        // 3M  fp16
    ushort_t* attb = Xh;                            // alias: Xh dead after gemm_qkv
    float2* rope   = (float2*)Woh;                  // 512 KB, dead after gemm_qkv

    cvt_f16<<<2048, 256, 0, stream>>>(X,    Xh,  (M_ * D_) / 8);
    cvt_f16<<<1536, 256, 0, stream>>>(Wqkv, Wh,  (NE_ * D_) / 8);
    rope_init<<<256, 256, 0, stream>>>(rope);

    gemm_qkv_f16<<<dim3(NE_ / 128, M_ / 128), 256, 0, stream>>>(Xh, Wh, rope, qb, kbuf, vtbuf);

    // Wo conversion AFTER gemm_qkv: Woh region holds the rope table until here
    cvt_f16<<<512, 256, 0, stream>>>(Wo, Woh, (D_ * D_) / 8);

    attn_mfma<<<B_ * H_ * (S_ / 128), 256, 0, stream>>>(qb, kbuf, vtbuf, attb);
    gemm_out_f16<<<dim3(D_ / 128, M_ / 64), 256, 0, stream>>>(attb, Woh, out);
}